// Round 7
// baseline (63.766 us; speedup 1.0000x reference)
//
#include <hip/hip_runtime.h>
#include <hip/hip_cooperative_groups.h>
#include <math.h>

namespace cg = cooperative_groups;

#define F_SIZE 26
#define F2 676
#define A 5
#define NUM_CLASSES 80
#define T 32
#define NB 128
#define CELLS (F2*A)            // 3380
#define UNITS 1024              // 128 batches x 8 octants
#define UCPB 423                // cells per octant (last octant: 419)
#define MAXGRID 1024
#define TPB 256

// ---------------- shared device routine pieces are inlined in both kernels ----------------

__global__ __launch_bounds__(TPB) void yolo_coop(
    const float* __restrict__ feat,
    const float* __restrict__ box_pred,
    const float* __restrict__ box_conf,
    const float* __restrict__ box_prob,
    const float* __restrict__ targets,
    const float* __restrict__ anchors,
    double* __restrict__ partial,
    float* __restrict__ out)
{
    __shared__ float4 tc[T];
    __shared__ float  ta[T];
    __shared__ float  tcls[T];
    __shared__ float  anc[2*A];
    __shared__ double dred[4];

    const int tid  = threadIdx.x;
    const int lane = tid & 63;
    const int wid  = tid >> 6;

    if (tid < 2*A) anc[tid] = anchors[tid];

    double acc = 0.0;

    for (int u = blockIdx.x; u < UNITS; u += gridDim.x) {
        const int b   = u >> 3;
        const int oct = u & 7;
        const size_t base = (size_t)b * CELLS;

        __syncthreads();   // all waves done with previous unit's LDS
        if (tid < T) {
            const float* tg = targets + ((size_t)b*T + tid)*5;
            float x1 = tg[0], y1 = tg[1], x2 = tg[2], y2 = tg[3];
            tc[tid]   = make_float4(x1, y1, x2, y2);
            ta[tid]   = (x2 - x1) * (y2 - y1);
            tcls[tid] = tg[4];
        }
        __syncthreads();

        // ---------------- background: covered test, up to 2 cells per thread ----------------
        const int i0 = oct*UCPB + tid;
        const int i1 = i0 + TPB;
        const bool a0 = (i0 < CELLS);
        const bool a1 = (tid < UCPB - TPB) && (i1 < CELLS);
        float4 p0 = make_float4(0.f,0.f,1.f,1.f), p1 = p0;
        float  c0 = 0.0f, c1 = 0.0f;
        if (a0) { p0 = *(const float4*)(box_pred + (base + i0)*4); c0 = box_conf[base + i0]; }
        if (a1) { p1 = *(const float4*)(box_pred + (base + i1)*4); c1 = box_conf[base + i1]; }
        {
            float px10 = p0.x - p0.z*0.5f, px20 = p0.x + p0.z*0.5f;
            float py10 = p0.y - p0.w*0.5f, py20 = p0.y + p0.w*0.5f;
            float pa0  = p0.z * p0.w;
            float px11 = p1.x - p1.z*0.5f, px21 = p1.x + p1.z*0.5f;
            float py11 = p1.y - p1.w*0.5f, py21 = p1.y + p1.w*0.5f;
            float pa1  = p1.z * p1.w;
            bool cov0 = false, cov1 = false;
            #pragma unroll
            for (int t = 0; t < T; t++) {
                float4 c = tc[t]; float tat = ta[t];
                float iw0 = fminf(px20, c.z) - fmaxf(px10, c.x);
                float ih0 = fminf(py20, c.w) - fmaxf(py10, c.y);
                iw0 = fmaxf(iw0, 0.0f); ih0 = fmaxf(ih0, 0.0f);
                cov0 = cov0 || (3.0f*(iw0*ih0) > pa0 + tat);  // best_iou>0.5 <=> 3*inter>pa+ta
                float iw1 = fminf(px21, c.z) - fmaxf(px11, c.x);
                float ih1 = fminf(py21, c.w) - fmaxf(py11, c.y);
                iw1 = fmaxf(iw1, 0.0f); ih1 = fmaxf(ih1, 0.0f);
                cov1 = cov1 || (3.0f*(iw1*ih1) > pa1 + tat);
            }
            if (a0 && !cov0) acc += 0.5 * (double)(c0*c0);
            if (a1 && !cov1) acc += 0.5 * (double)(c1*c1);
        }

        // ---------------- matched: wave wid owns target t = oct*4 + wid ----------------
        {
            const int t = oct*4 + wid;            // < 32
            const int l = lane & 31;
            const float4 c4 = tc[l];
            float x1 = c4.x, y1 = c4.y, x2 = c4.z, y2 = c4.w;
            float cx = (x1+x2)*(F_SIZE*0.5f), cy = (y1+y2)*(F_SIZE*0.5f);
            float tw = (x2-x1)*(float)F_SIZE,  th = (y2-y1)*(float)F_SIZE;
            float fx = floorf(cx), fy = floorf(cy);
            int pos = (int)(fy*(float)F_SIZE + fx);
            int bp = 0; float bi = -1.0f;
            #pragma unroll
            for (int a2 = 0; a2 < A; a2++) {
                float aw = anc[a2*2+0], ah = anc[a2*2+1];
                float inter = fminf(tw, aw) * fminf(th, ah);
                float iou = inter / (tw*th + aw*ah - inter);
                if (iou > bi) { bi = iou; bp = a2; }   // first-max (argmax)
            }
            const int my_pos = __shfl(pos, t);
            const int my_bp  = __shfl(bp,  t);
            bool lose = __ballot((lane < T) && (lane > t) && (pos == my_pos) && (bp == my_bp)) != 0ULL;

            if (!lose) {
                const size_t idx = base + (size_t)(my_pos*A + my_bp);
                const float4 pm = *(const float4*)(box_pred + idx*4);
                float px1 = pm.x - pm.z*0.5f, px2 = pm.x + pm.z*0.5f;
                float py1 = pm.y - pm.w*0.5f, py2 = pm.y + pm.w*0.5f;
                float parea = pm.z * pm.w;
                float iw = fminf(px2, x2) - fmaxf(px1, x1);
                float ih = fminf(py2, y2) - fmaxf(py1, y1);
                iw = fmaxf(iw, 0.0f); ih = fmaxf(ih, 0.0f);
                bool covered = __ballot((lane < T) && (3.0f*(iw*ih) > parea + ta[l])) != 0ULL;

                float cf = box_conf[idx];
                float df = 5.0f * (cf - 1.0f);
                double m = 0.5 * (double)(df*df);
                if (!covered) m -= 0.5 * (double)(cf*cf);   // compensate background add

                float mv0 = cx - fx, mv1 = cy - fy;
                float mv2 = logf(tw / anc[bp*2+0]);
                float mv3 = logf(th / anc[bp*2+1]);
                float M0 = __shfl(mv0, t), M1 = __shfl(mv1, t);
                float M2 = __shfl(mv2, t), M3 = __shfl(mv3, t);
                float MC = __shfl(tcls[l], t);

                const float4 f = *(const float4*)(feat + idx*4);
                float s0 = 1.0f/(1.0f + expf(-f.x));
                float s1 = 1.0f/(1.0f + expf(-f.y));
                float d0 = s0  - M0, d1 = s1  - M1;
                float d2 = f.z - M2, d3 = f.w - M3;
                m += 0.5 * (double)(d0*d0 + d1*d1 + d2*d2 + d3*d3);

                const float* pp = box_prob + idx*(size_t)NUM_CLASSES;
                float v0 = pp[lane];
                float v1 = (lane < 16) ? pp[64 + lane] : -3.0e38f;
                float mxv = fmaxf(v0, v1);
                #pragma unroll
                for (int o = 32; o >= 1; o >>= 1) mxv = fmaxf(mxv, __shfl_xor(mxv, o));
                float se = expf(v0 - mxv) + ((lane < 16) ? expf(v1 - mxv) : 0.0f);
                #pragma unroll
                for (int o = 32; o >= 1; o >>= 1) se += __shfl_xor(se, o);
                float lse = mxv + logf(se);
                float picked = pp[(int)MC];
                m += (double)(lse - picked);

                if (lane == 0) acc += m;
            }
        }
    }

    // ---------------- block partial -> release store ----------------
    #pragma unroll
    for (int o = 32; o >= 1; o >>= 1) acc += __shfl_down(acc, o);
    if (lane == 0) dred[wid] = acc;
    __syncthreads();
    if (tid == 0) {
        double v = dred[0] + dred[1] + dred[2] + dred[3];
        __hip_atomic_store(&partial[blockIdx.x], v, __ATOMIC_RELEASE, __HIP_MEMORY_SCOPE_AGENT);
    }

    cg::this_grid().sync();

    if (blockIdx.x == 0) {
        double a = 0.0;
        for (int i = tid; i < (int)gridDim.x; i += TPB)
            a += __hip_atomic_load(&partial[i], __ATOMIC_ACQUIRE, __HIP_MEMORY_SCOPE_AGENT);
        #pragma unroll
        for (int o = 32; o >= 1; o >>= 1) a += __shfl_down(a, o);
        __syncthreads();
        if (lane == 0) dred[wid] = a;
        __syncthreads();
        if (tid == 0) out[0] = (float)((dred[0]+dred[1]+dred[2]+dred[3]) / (double)NB);
    }
}

// ---------------- fallback: proven R5 two-kernel path ----------------

#define FB_CPB 845
#define FB_NBLK (NB*4)
#define FB_TPB 512

__global__ __launch_bounds__(FB_TPB, 4) void yolo_main_fb(
    const float* __restrict__ feat,
    const float* __restrict__ box_pred,
    const float* __restrict__ box_conf,
    const float* __restrict__ box_prob,
    const float* __restrict__ targets,
    const float* __restrict__ anchors,
    double* __restrict__ partial)
{
    __shared__ float4 tc[T];
    __shared__ float  ta[T];
    __shared__ float  tcls[T];
    __shared__ float  anc[2*A];
    __shared__ double dred[8];

    const int tid  = threadIdx.x;
    const int bid  = blockIdx.x;
    const int b    = bid >> 2;
    const int q    = bid & 3;
    const int lane = tid & 63;
    const int wid  = tid >> 6;

    const size_t base = (size_t)b * CELLS;
    const int i0 = q*FB_CPB + tid;
    const int i1 = i0 + FB_TPB;
    const bool a1 = (tid < FB_CPB - FB_TPB);

    float4 p0 = *(const float4*)(box_pred + (base + i0)*4);
    float  c0 = box_conf[base + i0];
    float4 p1 = make_float4(0.f,0.f,1.f,1.f);
    float  c1 = 0.0f;
    if (a1) { p1 = *(const float4*)(box_pred + (base + i1)*4); c1 = box_conf[base + i1]; }

    if (tid < T) {
        const float* tg = targets + ((size_t)b*T + tid)*5;
        float x1 = tg[0], y1 = tg[1], x2 = tg[2], y2 = tg[3];
        tc[tid]   = make_float4(x1, y1, x2, y2);
        ta[tid]   = (x2 - x1) * (y2 - y1);
        tcls[tid] = tg[4];
    }
    if (tid >= 64 && tid < 64 + 2*A) anc[tid - 64] = anchors[tid - 64];
    __syncthreads();

    double acc = 0.0;
    {
        float px10 = p0.x - p0.z*0.5f, px20 = p0.x + p0.z*0.5f;
        float py10 = p0.y - p0.w*0.5f, py20 = p0.y + p0.w*0.5f;
        float pa0  = p0.z * p0.w;
        float px11 = p1.x - p1.z*0.5f, px21 = p1.x + p1.z*0.5f;
        float py11 = p1.y - p1.w*0.5f, py21 = p1.y + p1.w*0.5f;
        float pa1  = p1.z * p1.w;
        bool cov0 = false, cov1 = false;
        #pragma unroll
        for (int t = 0; t < T; t++) {
            float4 c = tc[t]; float tat = ta[t];
            float iw0 = fminf(px20, c.z) - fmaxf(px10, c.x);
            float ih0 = fminf(py20, c.w) - fmaxf(py10, c.y);
            iw0 = fmaxf(iw0, 0.0f); ih0 = fmaxf(ih0, 0.0f);
            cov0 = cov0 || (3.0f*(iw0*ih0) > pa0 + tat);
            float iw1 = fminf(px21, c.z) - fmaxf(px11, c.x);
            float ih1 = fminf(py21, c.w) - fmaxf(py11, c.y);
            iw1 = fmaxf(iw1, 0.0f); ih1 = fmaxf(ih1, 0.0f);
            cov1 = cov1 || (3.0f*(iw1*ih1) > pa1 + tat);
        }
        if (!cov0)       acc += 0.5 * (double)(c0*c0);
        if (a1 && !cov1) acc += 0.5 * (double)(c1*c1);
    }
    {
        const int t = q*8 + wid;
        const int l = lane & 31;
        const float4 c4 = tc[l];
        float x1 = c4.x, y1 = c4.y, x2 = c4.z, y2 = c4.w;
        float cx = (x1+x2)*(F_SIZE*0.5f), cy = (y1+y2)*(F_SIZE*0.5f);
        float tw = (x2-x1)*(float)F_SIZE,  th = (y2-y1)*(float)F_SIZE;
        float fx = floorf(cx), fy = floorf(cy);
        int pos = (int)(fy*(float)F_SIZE + fx);
        int bp = 0; float bi = -1.0f;
        #pragma unroll
        for (int a2 = 0; a2 < A; a2++) {
            float aw = anc[a2*2+0], ah = anc[a2*2+1];
            float inter = fminf(tw, aw) * fminf(th, ah);
            float iou = inter / (tw*th + aw*ah - inter);
            if (iou > bi) { bi = iou; bp = a2; }
        }
        const int my_pos = __shfl(pos, t);
        const int my_bp  = __shfl(bp,  t);
        bool lose = __ballot((lane < T) && (lane > t) && (pos == my_pos) && (bp == my_bp)) != 0ULL;
        if (!lose) {
            const size_t idx = base + (size_t)(my_pos*A + my_bp);
            const float4 pm = *(const float4*)(box_pred + idx*4);
            float px1 = pm.x - pm.z*0.5f, px2 = pm.x + pm.z*0.5f;
            float py1 = pm.y - pm.w*0.5f, py2 = pm.y + pm.w*0.5f;
            float parea = pm.z * pm.w;
            float iw = fminf(px2, x2) - fmaxf(px1, x1);
            float ih = fminf(py2, y2) - fmaxf(py1, y1);
            iw = fmaxf(iw, 0.0f); ih = fmaxf(ih, 0.0f);
            bool covered = __ballot((lane < T) && (3.0f*(iw*ih) > parea + ta[l])) != 0ULL;

            float cf = box_conf[idx];
            float df = 5.0f * (cf - 1.0f);
            double m = 0.5 * (double)(df*df);
            if (!covered) m -= 0.5 * (double)(cf*cf);

            float mv0 = cx - fx, mv1 = cy - fy;
            float mv2 = logf(tw / anc[bp*2+0]);
            float mv3 = logf(th / anc[bp*2+1]);
            float M0 = __shfl(mv0, t), M1 = __shfl(mv1, t);
            float M2 = __shfl(mv2, t), M3 = __shfl(mv3, t);
            float MC = __shfl(tcls[l], t);

            const float4 f = *(const float4*)(feat + idx*4);
            float s0 = 1.0f/(1.0f + expf(-f.x));
            float s1 = 1.0f/(1.0f + expf(-f.y));
            float d0 = s0  - M0, d1 = s1  - M1;
            float d2 = f.z - M2, d3 = f.w - M3;
            m += 0.5 * (double)(d0*d0 + d1*d1 + d2*d2 + d3*d3);

            const float* pp = box_prob + idx*(size_t)NUM_CLASSES;
            float v0 = pp[lane];
            float v1 = (lane < 16) ? pp[64 + lane] : -3.0e38f;
            float mxv = fmaxf(v0, v1);
            #pragma unroll
            for (int o = 32; o >= 1; o >>= 1) mxv = fmaxf(mxv, __shfl_xor(mxv, o));
            float se = expf(v0 - mxv) + ((lane < 16) ? expf(v1 - mxv) : 0.0f);
            #pragma unroll
            for (int o = 32; o >= 1; o >>= 1) se += __shfl_xor(se, o);
            float lse = mxv + logf(se);
            float picked = pp[(int)MC];
            m += (double)(lse - picked);

            if (lane == 0) acc += m;
        }
    }

    #pragma unroll
    for (int o = 32; o >= 1; o >>= 1) acc += __shfl_down(acc, o);
    if (lane == 0) dred[wid] = acc;
    __syncthreads();
    if (tid == 0) {
        double v = 0.0;
        #pragma unroll
        for (int w = 0; w < 8; w++) v += dred[w];
        partial[bid] = v;
    }
}

__global__ __launch_bounds__(FB_TPB) void yolo_reduce_fb(const double* __restrict__ partial,
                                                         float* __restrict__ out)
{
    __shared__ double dred[8];
    const int tid  = threadIdx.x;
    const int lane = tid & 63;
    const int wid  = tid >> 6;
    double a = partial[tid];
    #pragma unroll
    for (int o = 32; o >= 1; o >>= 1) a += __shfl_down(a, o);
    if (lane == 0) dred[wid] = a;
    __syncthreads();
    if (tid == 0) {
        double s = 0.0;
        #pragma unroll
        for (int w = 0; w < 8; w++) s += dred[w];
        out[0] = (float)(s / (double)NB);
    }
}

extern "C" void kernel_launch(void* const* d_in, const int* in_sizes, int n_in,
                              void* d_out, int out_size, void* d_ws, size_t ws_size,
                              hipStream_t stream) {
    const float* feat     = (const float*)d_in[0];
    const float* box_pred = (const float*)d_in[1];
    const float* box_conf = (const float*)d_in[2];
    const float* box_prob = (const float*)d_in[3];
    const float* targets  = (const float*)d_in[4];
    const float* anchors  = (const float*)d_in[5];
    double* partial = (double*)d_ws;
    float* out = (float*)d_out;

    bool coop_done = false;
    int maxPerCU = 0;
    hipError_t qe = hipOccupancyMaxActiveBlocksPerMultiprocessor(
        &maxPerCU, (const void*)yolo_coop, TPB, 0);
    if (qe == hipSuccess && maxPerCU > 0) {
        int grid = maxPerCU * 256;          // 256 CUs on MI355X
        if (grid > MAXGRID) grid = MAXGRID;
        void* args[] = { (void*)&feat, (void*)&box_pred, (void*)&box_conf, (void*)&box_prob,
                         (void*)&targets, (void*)&anchors, (void*)&partial, (void*)&out };
        hipError_t e = hipLaunchCooperativeKernel((const void*)yolo_coop,
                                                  dim3(grid), dim3(TPB), args, 0, stream);
        coop_done = (e == hipSuccess);
    }
    if (!coop_done) {
        yolo_main_fb<<<FB_NBLK, FB_TPB, 0, stream>>>(
            feat, box_pred, box_conf, box_prob, targets, anchors, partial);
        yolo_reduce_fb<<<1, FB_TPB, 0, stream>>>(partial, out);
    }
}

// Round 8
// 26.990 us; speedup vs baseline: 2.3626x; 2.3626x over previous
//
#include <hip/hip_runtime.h>
#include <math.h>

#define F_SIZE 26
#define F2 676
#define A 5
#define NUM_CLASSES 80
#define T 32
#define NB 128
#define CELLS (F2*A)            // 3380 = 4 * 845
#define CPB 845                 // cells per block (one quarter-batch)
#define NBLK (NB*4)             // 512 blocks, each fully inside one batch
#define TPB 512
#define MAGIC 0x9E3779B97F4A7C15ULL

typedef unsigned long long u64;

__global__ __launch_bounds__(TPB, 4) void yolo_single(
    const float* __restrict__ feat,
    const float* __restrict__ box_pred,
    const float* __restrict__ box_conf,
    const float* __restrict__ box_prob,
    const float* __restrict__ targets,
    const float* __restrict__ anchors,
    u64* __restrict__ rec,              // [NBLK][4] u64 records: {v, ~v, v^MAGIC, pad}
    float* __restrict__ out)
{
    __shared__ float4 tc[T];
    __shared__ float  ta[T];
    __shared__ float  tcls[T];
    __shared__ float  anc[2*A];
    __shared__ double dred[8];

    const int tid  = threadIdx.x;
    const int bid  = blockIdx.x;
    const int b    = bid >> 2;          // batch
    const int q    = bid & 3;           // quarter within batch
    const int lane = tid & 63;
    const int wid  = tid >> 6;

    const size_t base = (size_t)b * CELLS;
    const int i0 = q*CPB + tid;         // always < 3380
    const int i1 = i0 + TPB;
    const bool a1 = (tid < CPB - TPB);  // tid < 333

    // ---- issue per-cell global loads first (hide behind LDS fill + barrier) ----
    float4 p0 = *(const float4*)(box_pred + (base + i0)*4);
    float  c0 = box_conf[base + i0];
    float4 p1 = make_float4(0.f,0.f,1.f,1.f);
    float  c1 = 0.0f;
    if (a1) { p1 = *(const float4*)(box_pred + (base + i1)*4); c1 = box_conf[base + i1]; }

    // ---- targets + anchors to LDS ----
    if (tid < T) {
        const float* tg = targets + ((size_t)b*T + tid)*5;
        float x1 = tg[0], y1 = tg[1], x2 = tg[2], y2 = tg[3];
        tc[tid]   = make_float4(x1, y1, x2, y2);
        ta[tid]   = (x2 - x1) * (y2 - y1);
        tcls[tid] = tg[4];
    }
    if (tid >= 64 && tid < 64 + 2*A) anc[tid - 64] = anchors[tid - 64];
    __syncthreads();

    double acc = 0.0;

    // ---------------- background: covered test, 1-2 cells per thread ----------------
    {
        float px10 = p0.x - p0.z*0.5f, px20 = p0.x + p0.z*0.5f;
        float py10 = p0.y - p0.w*0.5f, py20 = p0.y + p0.w*0.5f;
        float pa0  = p0.z * p0.w;
        float px11 = p1.x - p1.z*0.5f, px21 = p1.x + p1.z*0.5f;
        float py11 = p1.y - p1.w*0.5f, py21 = p1.y + p1.w*0.5f;
        float pa1  = p1.z * p1.w;
        bool cov0 = false, cov1 = false;
        #pragma unroll
        for (int t = 0; t < T; t++) {
            float4 c = tc[t]; float tat = ta[t];
            float iw0 = fminf(px20, c.z) - fmaxf(px10, c.x);
            float ih0 = fminf(py20, c.w) - fmaxf(py10, c.y);
            iw0 = fmaxf(iw0, 0.0f); ih0 = fmaxf(ih0, 0.0f);
            cov0 = cov0 || (3.0f*(iw0*ih0) > pa0 + tat);   // best_iou>0.5 <=> 3*inter>pa+ta
            float iw1 = fminf(px21, c.z) - fmaxf(px11, c.x);
            float ih1 = fminf(py21, c.w) - fmaxf(py11, c.y);
            iw1 = fmaxf(iw1, 0.0f); ih1 = fmaxf(ih1, 0.0f);
            cov1 = cov1 || (3.0f*(iw1*ih1) > pa1 + tat);
        }
        if (!cov0)       acc += 0.5 * (double)(c0*c0);
        if (a1 && !cov1) acc += 0.5 * (double)(c1*c1);
    }

    // ---------------- matched: wave wid owns target t = 8q + wid ----------------
    {
        const int t = q*8 + wid;              // always < 32
        const int l = lane & 31;              // lanes 32-63 duplicate 0-31
        const float4 c4 = tc[l];
        float x1 = c4.x, y1 = c4.y, x2 = c4.z, y2 = c4.w;
        float cx = (x1+x2)*(F_SIZE*0.5f), cy = (y1+y2)*(F_SIZE*0.5f);
        float tw = (x2-x1)*(float)F_SIZE,  th = (y2-y1)*(float)F_SIZE;
        float fx = floorf(cx), fy = floorf(cy);
        int pos = (int)(fy*(float)F_SIZE + fx);
        int bp = 0; float bi = -1.0f;
        #pragma unroll
        for (int a2 = 0; a2 < A; a2++) {
            float aw = anc[a2*2+0], ah = anc[a2*2+1];
            float inter = fminf(tw, aw) * fminf(th, ah);
            float iou = inter / (tw*th + aw*ah - inter);
            if (iou > bi) { bi = iou; bp = a2; }   // first-max (argmax)
        }
        const int my_pos = __shfl(pos, t);
        const int my_bp  = __shfl(bp,  t);
        // last-wins scatter: a higher-index target with the same (pos,anchor) wins
        bool lose = __ballot((lane < T) && (lane > t) && (pos == my_pos) && (bp == my_bp)) != 0ULL;

        if (!lose) {
            const size_t idx = base + (size_t)(my_pos*A + my_bp);

            // covered-bool for this cell, bit-identical arithmetic to background role
            const float4 pm = *(const float4*)(box_pred + idx*4);
            float px1 = pm.x - pm.z*0.5f, px2 = pm.x + pm.z*0.5f;
            float py1 = pm.y - pm.w*0.5f, py2 = pm.y + pm.w*0.5f;
            float parea = pm.z * pm.w;
            float iw = fminf(px2, x2) - fmaxf(px1, x1);
            float ih = fminf(py2, y2) - fmaxf(py1, y1);
            iw = fmaxf(iw, 0.0f); ih = fmaxf(ih, 0.0f);
            bool covered = __ballot((lane < T) && (3.0f*(iw*ih) > parea + ta[l])) != 0ULL;

            float cf = box_conf[idx];
            float df = 5.0f * (cf - 1.0f);
            double m = 0.5 * (double)(df*df);
            if (!covered) m -= 0.5 * (double)(cf*cf);   // compensate background add

            float mv0 = cx - fx, mv1 = cy - fy;
            float mv2 = logf(tw / anc[bp*2+0]);
            float mv3 = logf(th / anc[bp*2+1]);
            float M0 = __shfl(mv0, t), M1 = __shfl(mv1, t);
            float M2 = __shfl(mv2, t), M3 = __shfl(mv3, t);
            float MC = __shfl(tcls[l], t);

            const float4 f = *(const float4*)(feat + idx*4);
            float s0 = 1.0f/(1.0f + expf(-f.x));
            float s1 = 1.0f/(1.0f + expf(-f.y));
            float d0 = s0  - M0, d1 = s1  - M1;
            float d2 = f.z - M2, d3 = f.w - M3;
            m += 0.5 * (double)(d0*d0 + d1*d1 + d2*d2 + d3*d3);

            // class loss: wave-parallel LSE over 80 logits
            const float* pp = box_prob + idx*(size_t)NUM_CLASSES;
            float v0 = pp[lane];
            float v1 = (lane < 16) ? pp[64 + lane] : -3.0e38f;
            float mxv = fmaxf(v0, v1);
            #pragma unroll
            for (int o = 32; o >= 1; o >>= 1) mxv = fmaxf(mxv, __shfl_xor(mxv, o));
            float se = expf(v0 - mxv) + ((lane < 16) ? expf(v1 - mxv) : 0.0f);
            #pragma unroll
            for (int o = 32; o >= 1; o >>= 1) se += __shfl_xor(se, o);
            float lse = mxv + logf(se);
            float picked = pp[(int)MC];
            m += (double)(lse - picked);

            if (lane == 0) acc += m;   // wave contributes once
        }
    }

    // ---------------- block reduction: wave shfl -> 8 doubles -> block partial ----------------
    #pragma unroll
    for (int o = 32; o >= 1; o >>= 1) acc += __shfl_down(acc, o);
    if (lane == 0) dred[wid] = acc;
    __syncthreads();

    if (bid != 0) {
        // publish self-validating record {v, ~v, v^MAGIC}; then done
        if (tid == 0) {
            double v = 0.0;
            #pragma unroll
            for (int w = 0; w < 8; w++) v += dred[w];
            u64 x = (u64)__double_as_longlong(v);
            __hip_atomic_store(&rec[bid*4+0], x,         __ATOMIC_RELEASE, __HIP_MEMORY_SCOPE_AGENT);
            __hip_atomic_store(&rec[bid*4+1], ~x,        __ATOMIC_RELEASE, __HIP_MEMORY_SCOPE_AGENT);
            __hip_atomic_store(&rec[bid*4+2], x ^ MAGIC, __ATOMIC_RELEASE, __HIP_MEMORY_SCOPE_AGENT);
        }
        return;
    }

    // ---------------- block 0: gather all records (spin until valid), final reduce ----------------
    double v = 0.0;
    if (tid == 0) {
        #pragma unroll
        for (int w = 0; w < 8; w++) v += dred[w];       // block 0's own partial
    } else {
        const u64* r = &rec[tid*4];                     // thread t <-> block t (1..511)
        for (;;) {
            u64 x = __hip_atomic_load(&r[0], __ATOMIC_ACQUIRE, __HIP_MEMORY_SCOPE_AGENT);
            u64 y = __hip_atomic_load(&r[1], __ATOMIC_ACQUIRE, __HIP_MEMORY_SCOPE_AGENT);
            u64 z = __hip_atomic_load(&r[2], __ATOMIC_ACQUIRE, __HIP_MEMORY_SCOPE_AGENT);
            if (y == ~x && z == (x ^ MAGIC)) { v = __longlong_as_double((long long)x); break; }
            __builtin_amdgcn_s_sleep(8);
        }
    }
    __syncthreads();                                    // dred safe to reuse
    #pragma unroll
    for (int o = 32; o >= 1; o >>= 1) v += __shfl_down(v, o);
    if (lane == 0) dred[wid] = v;
    __syncthreads();
    if (tid == 0) {
        double s = 0.0;
        #pragma unroll
        for (int w = 0; w < 8; w++) s += dred[w];
        out[0] = (float)(s / (double)NB);
    }
}

extern "C" void kernel_launch(void* const* d_in, const int* in_sizes, int n_in,
                              void* d_out, int out_size, void* d_ws, size_t ws_size,
                              hipStream_t stream) {
    const float* feat     = (const float*)d_in[0];
    const float* box_pred = (const float*)d_in[1];
    const float* box_conf = (const float*)d_in[2];
    const float* box_prob = (const float*)d_in[3];
    const float* targets  = (const float*)d_in[4];
    const float* anchors  = (const float*)d_in[5];
    u64*  rec = (u64*)d_ws;            // NBLK*4 u64 = 16 KB, records 1..511 rewritten each launch
    float* out = (float*)d_out;

    yolo_single<<<NBLK, TPB, 0, stream>>>(
        feat, box_pred, box_conf, box_prob, targets, anchors, rec, out);
}

// Round 9
// 19.594 us; speedup vs baseline: 3.2544x; 1.3775x over previous
//
#include <hip/hip_runtime.h>
#include <math.h>

#define F_SIZE 26
#define F2 676
#define A 5
#define NUM_CLASSES 80
#define T 32
#define NB 128
#define CELLS (F2*A)            // 3380 = 10 * 338
#define NCH 10                  // chunks per batch
#define CPB 338                 // cells per chunk (== one per thread)
#define NBLK (NB*NCH)           // 1280 blocks
#define TPB 384                 // 6 waves
#define RED_TPB 256

__global__ __launch_bounds__(TPB) void yolo_main(
    const float* __restrict__ feat,
    const float* __restrict__ box_pred,
    const float* __restrict__ box_conf,
    const float* __restrict__ box_prob,
    const float* __restrict__ targets,
    const float* __restrict__ anchors,
    double* __restrict__ partial)
{
    __shared__ float4 tc[T];
    __shared__ float  ta[T];
    __shared__ float  tcls[T];
    __shared__ float  anc[2*A];
    __shared__ double dred[6];

    const int tid  = threadIdx.x;
    const int bid  = blockIdx.x;
    const int b    = bid / NCH;         // batch
    const int q    = bid % NCH;         // chunk within batch
    const int lane = tid & 63;
    const int wid  = tid >> 6;

    const size_t base = (size_t)b * CELLS;
    const int i0 = q*CPB + tid;         // < 3380 when tid < 338
    const bool a0 = (tid < CPB);

    // ---- issue per-cell global loads first (hide behind LDS fill + barrier) ----
    float4 p0 = make_float4(0.f, 0.f, 1.f, 1.f);
    float  c0 = 0.0f;
    if (a0) {
        p0 = *(const float4*)(box_pred + (base + i0)*4);
        c0 = box_conf[base + i0];
    }

    // ---- targets + anchors to LDS ----
    if (tid < T) {
        const float* tg = targets + ((size_t)b*T + tid)*5;
        float x1 = tg[0], y1 = tg[1], x2 = tg[2], y2 = tg[3];
        tc[tid]   = make_float4(x1, y1, x2, y2);
        ta[tid]   = (x2 - x1) * (y2 - y1);
        tcls[tid] = tg[4];
    }
    if (tid >= 64 && tid < 64 + 2*A) anc[tid - 64] = anchors[tid - 64];
    __syncthreads();

    double acc = 0.0;

    // ---------------- background: covered test, exactly 1 cell per thread ----------------
    {
        float px10 = p0.x - p0.z*0.5f, px20 = p0.x + p0.z*0.5f;
        float py10 = p0.y - p0.w*0.5f, py20 = p0.y + p0.w*0.5f;
        float pa0  = p0.z * p0.w;
        bool cov0 = false;
        #pragma unroll
        for (int t = 0; t < T; t++) {
            float4 c = tc[t]; float tat = ta[t];
            float iw0 = fminf(px20, c.z) - fmaxf(px10, c.x);
            float ih0 = fminf(py20, c.w) - fmaxf(py10, c.y);
            iw0 = fmaxf(iw0, 0.0f); ih0 = fmaxf(ih0, 0.0f);
            cov0 = cov0 || (3.0f*(iw0*ih0) > pa0 + tat);   // best_iou>0.5 <=> 3*inter>pa+ta
        }
        if (a0 && !cov0) acc += 0.5 * (double)(c0*c0);
    }

    // ---------------- matched: wave slot = q*6 + wid owns target t = slot (<32) ----------------
    {
        const int t = q*6 + wid;              // 0..59; only t<32 valid
        if (t < T) {
            const int l = lane & 31;          // lanes 32-63 duplicate 0-31
            const float4 c4 = tc[l];
            float x1 = c4.x, y1 = c4.y, x2 = c4.z, y2 = c4.w;
            float cx = (x1+x2)*(F_SIZE*0.5f), cy = (y1+y2)*(F_SIZE*0.5f);
            float tw = (x2-x1)*(float)F_SIZE,  th = (y2-y1)*(float)F_SIZE;
            float fx = floorf(cx), fy = floorf(cy);
            int pos = (int)(fy*(float)F_SIZE + fx);
            int bp = 0; float bi = -1.0f;
            #pragma unroll
            for (int a2 = 0; a2 < A; a2++) {
                float aw = anc[a2*2+0], ah = anc[a2*2+1];
                float inter = fminf(tw, aw) * fminf(th, ah);
                float iou = inter / (tw*th + aw*ah - inter);
                if (iou > bi) { bi = iou; bp = a2; }   // first-max (argmax)
            }
            const int my_pos = __shfl(pos, t);
            const int my_bp  = __shfl(bp,  t);
            // last-wins scatter: a higher-index target with the same (pos,anchor) wins
            bool lose = __ballot((lane < T) && (lane > t) && (pos == my_pos) && (bp == my_bp)) != 0ULL;

            if (!lose) {
                const size_t idx = base + (size_t)(my_pos*A + my_bp);

                // covered-bool for this cell, bit-identical arithmetic to background role
                const float4 pm = *(const float4*)(box_pred + idx*4);
                float px1 = pm.x - pm.z*0.5f, px2 = pm.x + pm.z*0.5f;
                float py1 = pm.y - pm.w*0.5f, py2 = pm.y + pm.w*0.5f;
                float parea = pm.z * pm.w;
                float iw = fminf(px2, x2) - fmaxf(px1, x1);
                float ih = fminf(py2, y2) - fmaxf(py1, y1);
                iw = fmaxf(iw, 0.0f); ih = fmaxf(ih, 0.0f);
                bool covered = __ballot((lane < T) && (3.0f*(iw*ih) > parea + ta[l])) != 0ULL;

                float cf = box_conf[idx];
                float df = 5.0f * (cf - 1.0f);
                double m = 0.5 * (double)(df*df);
                if (!covered) m -= 0.5 * (double)(cf*cf);   // compensate background add

                float mv0 = cx - fx, mv1 = cy - fy;
                float mv2 = logf(tw / anc[bp*2+0]);
                float mv3 = logf(th / anc[bp*2+1]);
                float M0 = __shfl(mv0, t), M1 = __shfl(mv1, t);
                float M2 = __shfl(mv2, t), M3 = __shfl(mv3, t);
                float MC = __shfl(tcls[l], t);

                const float4 f = *(const float4*)(feat + idx*4);
                float s0 = 1.0f/(1.0f + expf(-f.x));
                float s1 = 1.0f/(1.0f + expf(-f.y));
                float d0 = s0  - M0, d1 = s1  - M1;
                float d2 = f.z - M2, d3 = f.w - M3;
                m += 0.5 * (double)(d0*d0 + d1*d1 + d2*d2 + d3*d3);

                // class loss: wave-parallel LSE over 80 logits
                const float* pp = box_prob + idx*(size_t)NUM_CLASSES;
                float v0 = pp[lane];
                float v1 = (lane < 16) ? pp[64 + lane] : -3.0e38f;
                float mxv = fmaxf(v0, v1);
                #pragma unroll
                for (int o = 32; o >= 1; o >>= 1) mxv = fmaxf(mxv, __shfl_xor(mxv, o));
                float se = expf(v0 - mxv) + ((lane < 16) ? expf(v1 - mxv) : 0.0f);
                #pragma unroll
                for (int o = 32; o >= 1; o >>= 1) se += __shfl_xor(se, o);
                float lse = mxv + logf(se);
                float picked = pp[(int)MC];
                m += (double)(lse - picked);

                if (lane == 0) acc += m;   // wave contributes once
            }
        }
    }

    // ---------------- reduction: wave shfl -> 6 doubles -> plain store ----------------
    #pragma unroll
    for (int o = 32; o >= 1; o >>= 1) acc += __shfl_down(acc, o);
    if (lane == 0) dred[wid] = acc;
    __syncthreads();
    if (tid == 0) {
        double v = 0.0;
        #pragma unroll
        for (int w = 0; w < 6; w++) v += dred[w];
        partial[bid] = v;
    }
}

__global__ __launch_bounds__(RED_TPB) void yolo_reduce(const double* __restrict__ partial,
                                                       float* __restrict__ out)
{
    __shared__ double dred[4];
    const int tid  = threadIdx.x;
    const int lane = tid & 63;
    const int wid  = tid >> 6;
    double a = 0.0;
    #pragma unroll
    for (int k = 0; k < 5; k++) a += partial[tid + k*RED_TPB];   // 1280 = 256*5
    #pragma unroll
    for (int o = 32; o >= 1; o >>= 1) a += __shfl_down(a, o);
    if (lane == 0) dred[wid] = a;
    __syncthreads();
    if (tid == 0) {
        double s = dred[0] + dred[1] + dred[2] + dred[3];
        out[0] = (float)(s / (double)NB);
    }
}

extern "C" void kernel_launch(void* const* d_in, const int* in_sizes, int n_in,
                              void* d_out, int out_size, void* d_ws, size_t ws_size,
                              hipStream_t stream) {
    const float* feat     = (const float*)d_in[0];
    const float* box_pred = (const float*)d_in[1];
    const float* box_conf = (const float*)d_in[2];
    const float* box_prob = (const float*)d_in[3];
    const float* targets  = (const float*)d_in[4];
    const float* anchors  = (const float*)d_in[5];
    double* partial = (double*)d_ws;   // NBLK doubles, fully overwritten each launch
    float* out = (float*)d_out;

    yolo_main<<<NBLK, TPB, 0, stream>>>(
        feat, box_pred, box_conf, box_prob, targets, anchors, partial);
    yolo_reduce<<<1, RED_TPB, 0, stream>>>(partial, out);
}

// Round 10
// 18.990 us; speedup vs baseline: 3.3580x; 1.0318x over previous
//
#include <hip/hip_runtime.h>
#include <math.h>

#define F_SIZE 26
#define F2 676
#define A 5
#define NUM_CLASSES 80
#define T 32
#define NB 128
#define CELLS (F2*A)            // 3380 = 2 * 1690
#define HCPB 1690               // cells per block (half batch)
#define NBLK (NB*2)             // 256 blocks
#define TPB 512

__global__ __launch_bounds__(TPB) void yolo_main(
    const float* __restrict__ feat,
    const float* __restrict__ box_pred,
    const float* __restrict__ box_conf,
    const float* __restrict__ box_prob,
    const float* __restrict__ targets,
    const float* __restrict__ anchors,
    double* __restrict__ partial)
{
    __shared__ float4 tc[T];
    __shared__ float  ta[T];
    __shared__ float  tcls[T];
    __shared__ float  anc[2*A];
    __shared__ double dred[8];

    const int tid  = threadIdx.x;
    const int bid  = blockIdx.x;
    const int b    = bid >> 1;          // batch
    const int q    = bid & 1;           // half within batch
    const int lane = tid & 63;
    const int wid  = tid >> 6;

    const size_t base = (size_t)b * CELLS;
    const int cbase = q*HCPB;

    // ---- issue per-cell global loads first (hide behind LDS fill + barrier) ----
    // k = 0,1,2 always valid (tid + 2*512 + cbase <= 1690+1535 < 3380); k=3 only tid < 154
    float4 p[4]; float cf[4];
    const bool a3 = (tid < HCPB - 3*TPB);   // tid < 154
    #pragma unroll
    for (int k = 0; k < 4; k++) { p[k] = make_float4(0.f,0.f,1.f,1.f); cf[k] = 0.0f; }
    #pragma unroll
    for (int k = 0; k < 3; k++) {
        const size_t i = base + cbase + tid + k*TPB;
        p[k]  = *(const float4*)(box_pred + i*4);
        cf[k] = box_conf[i];
    }
    if (a3) {
        const size_t i = base + cbase + tid + 3*TPB;
        p[3]  = *(const float4*)(box_pred + i*4);
        cf[3] = box_conf[i];
    }

    // ---- targets + anchors to LDS ----
    if (tid < T) {
        const float* tg = targets + ((size_t)b*T + tid)*5;
        float x1 = tg[0], y1 = tg[1], x2 = tg[2], y2 = tg[3];
        tc[tid]   = make_float4(x1, y1, x2, y2);
        ta[tid]   = (x2 - x1) * (y2 - y1);
        tcls[tid] = tg[4];
    }
    if (tid >= 64 && tid < 64 + 2*A) anc[tid - 64] = anchors[tid - 64];
    __syncthreads();

    double acc = 0.0;

    // ---------------- background: covered test, 3-4 cells per thread ----------------
    {
        float px1[4], px2[4], py1[4], py2[4], pa[4];
        bool cov[4];
        #pragma unroll
        for (int k = 0; k < 4; k++) {
            px1[k] = p[k].x - p[k].z*0.5f;  px2[k] = p[k].x + p[k].z*0.5f;
            py1[k] = p[k].y - p[k].w*0.5f;  py2[k] = p[k].y + p[k].w*0.5f;
            pa[k]  = p[k].z * p[k].w;
            cov[k] = false;
        }
        #pragma unroll
        for (int t = 0; t < T; t++) {
            float4 c = tc[t]; float tat = ta[t];
            #pragma unroll
            for (int k = 0; k < 4; k++) {
                float iw = fminf(px2[k], c.z) - fmaxf(px1[k], c.x);
                float ih = fminf(py2[k], c.w) - fmaxf(py1[k], c.y);
                iw = fmaxf(iw, 0.0f); ih = fmaxf(ih, 0.0f);
                cov[k] = cov[k] || (3.0f*(iw*ih) > pa[k] + tat);  // best_iou>0.5 <=> 3*inter>pa+ta
            }
        }
        #pragma unroll
        for (int k = 0; k < 3; k++)
            if (!cov[k]) acc += 0.5 * (double)(cf[k]*cf[k]);
        if (a3 && !cov[3]) acc += 0.5 * (double)(cf[3]*cf[3]);
    }

    // ---------------- matched: wave wid owns targets q*16+wid and q*16+8+wid ----------------
    {
        // per-lane prep for all 32 targets (computed once, reused by both passes)
        const int l = lane & 31;              // lanes 32-63 duplicate 0-31
        const float4 c4 = tc[l];
        float x1 = c4.x, y1 = c4.y, x2 = c4.z, y2 = c4.w;
        float cx = (x1+x2)*(F_SIZE*0.5f), cy = (y1+y2)*(F_SIZE*0.5f);
        float tw = (x2-x1)*(float)F_SIZE,  th = (y2-y1)*(float)F_SIZE;
        float fx = floorf(cx), fy = floorf(cy);
        int pos = (int)(fy*(float)F_SIZE + fx);
        int bp = 0; float bi = -1.0f;
        #pragma unroll
        for (int a2 = 0; a2 < A; a2++) {
            float aw = anc[a2*2+0], ah = anc[a2*2+1];
            float inter = fminf(tw, aw) * fminf(th, ah);
            float iou = inter / (tw*th + aw*ah - inter);
            if (iou > bi) { bi = iou; bp = a2; }   // first-max (argmax)
        }
        float mv0 = cx - fx, mv1 = cy - fy;
        float mv2 = logf(tw / anc[bp*2+0]);
        float mv3 = logf(th / anc[bp*2+1]);
        float tcl = tcls[l];

        #pragma unroll
        for (int pass = 0; pass < 2; ++pass) {
            const int t = q*16 + pass*8 + wid;    // q=0: 0-15, q=1: 16-31
            const int my_pos = __shfl(pos, t);
            const int my_bp  = __shfl(bp,  t);
            // last-wins scatter: a higher-index target with the same (pos,anchor) wins
            bool lose = __ballot((lane < T) && (lane > t) && (pos == my_pos) && (bp == my_bp)) != 0ULL;
            if (lose) continue;

            const size_t idx = base + (size_t)(my_pos*A + my_bp);

            // covered-bool for this cell, bit-identical arithmetic to background role
            const float4 pm = *(const float4*)(box_pred + idx*4);
            float px1 = pm.x - pm.z*0.5f, px2 = pm.x + pm.z*0.5f;
            float py1 = pm.y - pm.w*0.5f, py2 = pm.y + pm.w*0.5f;
            float parea = pm.z * pm.w;
            float iw = fminf(px2, x2) - fmaxf(px1, x1);
            float ih = fminf(py2, y2) - fmaxf(py1, y1);
            iw = fmaxf(iw, 0.0f); ih = fmaxf(ih, 0.0f);
            bool covered = __ballot((lane < T) && (3.0f*(iw*ih) > parea + ta[l])) != 0ULL;

            float c1 = box_conf[idx];
            float df = 5.0f * (c1 - 1.0f);
            double m = 0.5 * (double)(df*df);
            if (!covered) m -= 0.5 * (double)(c1*c1);   // compensate background add

            float M0 = __shfl(mv0, t), M1 = __shfl(mv1, t);
            float M2 = __shfl(mv2, t), M3 = __shfl(mv3, t);
            float MC = __shfl(tcl, t);

            const float4 f = *(const float4*)(feat + idx*4);
            float s0 = 1.0f/(1.0f + expf(-f.x));
            float s1 = 1.0f/(1.0f + expf(-f.y));
            float d0 = s0  - M0, d1 = s1  - M1;
            float d2 = f.z - M2, d3 = f.w - M3;
            m += 0.5 * (double)(d0*d0 + d1*d1 + d2*d2 + d3*d3);

            // class loss: wave-parallel LSE over 80 logits
            const float* pp = box_prob + idx*(size_t)NUM_CLASSES;
            float v0 = pp[lane];
            float v1 = (lane < 16) ? pp[64 + lane] : -3.0e38f;
            float mxv = fmaxf(v0, v1);
            #pragma unroll
            for (int o = 32; o >= 1; o >>= 1) mxv = fmaxf(mxv, __shfl_xor(mxv, o));
            float se = expf(v0 - mxv) + ((lane < 16) ? expf(v1 - mxv) : 0.0f);
            #pragma unroll
            for (int o = 32; o >= 1; o >>= 1) se += __shfl_xor(se, o);
            float lse = mxv + logf(se);
            float picked = pp[(int)MC];
            m += (double)(lse - picked);

            if (lane == 0) acc += m;   // wave contributes once per target
        }
    }

    // ---------------- reduction: wave shfl -> 8 doubles -> plain store ----------------
    #pragma unroll
    for (int o = 32; o >= 1; o >>= 1) acc += __shfl_down(acc, o);
    if (lane == 0) dred[wid] = acc;
    __syncthreads();
    if (tid == 0) {
        double v = 0.0;
        #pragma unroll
        for (int w = 0; w < 8; w++) v += dred[w];
        partial[bid] = v;
    }
}

__global__ __launch_bounds__(256) void yolo_reduce(const double* __restrict__ partial,
                                                   float* __restrict__ out)
{
    __shared__ double dred[4];
    const int tid  = threadIdx.x;
    const int lane = tid & 63;
    const int wid  = tid >> 6;
    double a = partial[tid];            // 256 partials, 256 threads
    #pragma unroll
    for (int o = 32; o >= 1; o >>= 1) a += __shfl_down(a, o);
    if (lane == 0) dred[wid] = a;
    __syncthreads();
    if (tid == 0) {
        double s = dred[0] + dred[1] + dred[2] + dred[3];
        out[0] = (float)(s / (double)NB);
    }
}

extern "C" void kernel_launch(void* const* d_in, const int* in_sizes, int n_in,
                              void* d_out, int out_size, void* d_ws, size_t ws_size,
                              hipStream_t stream) {
    const float* feat     = (const float*)d_in[0];
    const float* box_pred = (const float*)d_in[1];
    const float* box_conf = (const float*)d_in[2];
    const float* box_prob = (const float*)d_in[3];
    const float* targets  = (const float*)d_in[4];
    const float* anchors  = (const float*)d_in[5];
    double* partial = (double*)d_ws;   // NBLK doubles, fully overwritten each launch
    float* out = (float*)d_out;

    yolo_main<<<NBLK, TPB, 0, stream>>>(
        feat, box_pred, box_conf, box_prob, targets, anchors, partial);
    yolo_reduce<<<1, 256, 0, stream>>>(partial, out);
}

// Round 11
// 17.216 us; speedup vs baseline: 3.7039x; 1.1030x over previous
//
#include <hip/hip_runtime.h>
#include <math.h>

#define F_SIZE 26
#define F2 676
#define A 5
#define NUM_CLASSES 80
#define T 32
#define NB 128
#define CELLS (F2*A)            // 3380 = 4 * 845
#define CPB 845                 // cells per block (one quarter-batch)
#define NBLK (NB*4)             // 512 blocks, each fully inside one batch
#define TPB 512

__global__ __launch_bounds__(TPB, 4) void yolo_main(
    const float* __restrict__ feat,
    const float* __restrict__ box_pred,
    const float* __restrict__ box_conf,
    const float* __restrict__ box_prob,
    const float* __restrict__ targets,
    const float* __restrict__ anchors,
    double* __restrict__ partial)
{
    __shared__ float4 tc[T];
    __shared__ float  ta[T];
    __shared__ float  tcls[T];
    __shared__ float  anc[2*A];
    __shared__ double dred[8];

    const int tid  = threadIdx.x;
    const int bid  = blockIdx.x;
    const int b    = bid >> 2;          // batch
    const int q    = bid & 3;           // quarter within batch
    const int lane = tid & 63;
    const int wid  = tid >> 6;

    const size_t base = (size_t)b * CELLS;
    const int i0 = q*CPB + tid;         // always < 3380
    const int i1 = i0 + TPB;
    const bool a1 = (tid < CPB - TPB);  // tid < 333

    // ---- issue per-cell global loads first (hide behind LDS fill + barrier) ----
    float4 p0 = *(const float4*)(box_pred + (base + i0)*4);
    float  c0 = box_conf[base + i0];
    float4 p1 = make_float4(0.f,0.f,1.f,1.f);
    float  c1 = 0.0f;
    if (a1) { p1 = *(const float4*)(box_pred + (base + i1)*4); c1 = box_conf[base + i1]; }

    // ---- targets + anchors to LDS ----
    if (tid < T) {
        const float* tg = targets + ((size_t)b*T + tid)*5;
        float x1 = tg[0], y1 = tg[1], x2 = tg[2], y2 = tg[3];
        tc[tid]   = make_float4(x1, y1, x2, y2);
        ta[tid]   = (x2 - x1) * (y2 - y1);
        tcls[tid] = tg[4];
    }
    if (tid >= 64 && tid < 64 + 2*A) anc[tid - 64] = anchors[tid - 64];
    __syncthreads();

    double acc = 0.0;

    // ---------------- background: covered test, 1-2 cells per thread ----------------
    {
        float px10 = p0.x - p0.z*0.5f, px20 = p0.x + p0.z*0.5f;
        float py10 = p0.y - p0.w*0.5f, py20 = p0.y + p0.w*0.5f;
        float pa0  = p0.z * p0.w;
        float px11 = p1.x - p1.z*0.5f, px21 = p1.x + p1.z*0.5f;
        float py11 = p1.y - p1.w*0.5f, py21 = p1.y + p1.w*0.5f;
        float pa1  = p1.z * p1.w;
        bool cov0 = false, cov1 = false;
        #pragma unroll
        for (int t = 0; t < T; t++) {
            float4 c = tc[t]; float tat = ta[t];
            float iw0 = fminf(px20, c.z) - fmaxf(px10, c.x);
            float ih0 = fminf(py20, c.w) - fmaxf(py10, c.y);
            iw0 = fmaxf(iw0, 0.0f); ih0 = fmaxf(ih0, 0.0f);
            cov0 = cov0 || (3.0f*(iw0*ih0) > pa0 + tat);   // best_iou>0.5 <=> 3*inter>pa+ta
            float iw1 = fminf(px21, c.z) - fmaxf(px11, c.x);
            float ih1 = fminf(py21, c.w) - fmaxf(py11, c.y);
            iw1 = fmaxf(iw1, 0.0f); ih1 = fmaxf(ih1, 0.0f);
            cov1 = cov1 || (3.0f*(iw1*ih1) > pa1 + tat);
        }
        if (!cov0)       acc += 0.5 * (double)(c0*c0);
        if (a1 && !cov1) acc += 0.5 * (double)(c1*c1);
    }

    // ---------------- matched: wave wid owns target t = 8q + wid ----------------
    {
        const int t = q*8 + wid;              // always < 32
        const int l = lane & 31;              // lanes 32-63 duplicate 0-31
        const float4 c4 = tc[l];
        float x1 = c4.x, y1 = c4.y, x2 = c4.z, y2 = c4.w;
        float cx = (x1+x2)*(F_SIZE*0.5f), cy = (y1+y2)*(F_SIZE*0.5f);
        float tw = (x2-x1)*(float)F_SIZE,  th = (y2-y1)*(float)F_SIZE;
        float fx = floorf(cx), fy = floorf(cy);
        int pos = (int)(fy*(float)F_SIZE + fx);
        int bp = 0; float bi = -1.0f;
        #pragma unroll
        for (int a2 = 0; a2 < A; a2++) {
            float aw = anc[a2*2+0], ah = anc[a2*2+1];
            float inter = fminf(tw, aw) * fminf(th, ah);
            float iou = inter / (tw*th + aw*ah - inter);
            if (iou > bi) { bi = iou; bp = a2; }   // first-max (argmax)
        }
        const int my_pos = __shfl(pos, t);
        const int my_bp  = __shfl(bp,  t);
        // last-wins scatter: a higher-index target with the same (pos,anchor) wins
        bool lose = __ballot((lane < T) && (lane > t) && (pos == my_pos) && (bp == my_bp)) != 0ULL;

        if (!lose) {
            const size_t idx = base + (size_t)(my_pos*A + my_bp);

            // covered-bool for this cell, bit-identical arithmetic to background role
            const float4 pm = *(const float4*)(box_pred + idx*4);
            float px1 = pm.x - pm.z*0.5f, px2 = pm.x + pm.z*0.5f;
            float py1 = pm.y - pm.w*0.5f, py2 = pm.y + pm.w*0.5f;
            float parea = pm.z * pm.w;
            float iw = fminf(px2, x2) - fmaxf(px1, x1);
            float ih = fminf(py2, y2) - fmaxf(py1, y1);
            iw = fmaxf(iw, 0.0f); ih = fmaxf(ih, 0.0f);
            bool covered = __ballot((lane < T) && (3.0f*(iw*ih) > parea + ta[l])) != 0ULL;

            float cf = box_conf[idx];
            float df = 5.0f * (cf - 1.0f);
            double m = 0.5 * (double)(df*df);
            if (!covered) m -= 0.5 * (double)(cf*cf);   // compensate background add

            float mv0 = cx - fx, mv1 = cy - fy;
            float mv2 = logf(tw / anc[bp*2+0]);
            float mv3 = logf(th / anc[bp*2+1]);
            float M0 = __shfl(mv0, t), M1 = __shfl(mv1, t);
            float M2 = __shfl(mv2, t), M3 = __shfl(mv3, t);
            float MC = __shfl(tcls[l], t);

            const float4 f = *(const float4*)(feat + idx*4);
            float s0 = 1.0f/(1.0f + expf(-f.x));
            float s1 = 1.0f/(1.0f + expf(-f.y));
            float d0 = s0  - M0, d1 = s1  - M1;
            float d2 = f.z - M2, d3 = f.w - M3;
            m += 0.5 * (double)(d0*d0 + d1*d1 + d2*d2 + d3*d3);

            // class loss: wave-parallel LSE over 80 logits
            const float* pp = box_prob + idx*(size_t)NUM_CLASSES;
            float v0 = pp[lane];
            float v1 = (lane < 16) ? pp[64 + lane] : -3.0e38f;
            float mxv = fmaxf(v0, v1);
            #pragma unroll
            for (int o = 32; o >= 1; o >>= 1) mxv = fmaxf(mxv, __shfl_xor(mxv, o));
            float se = expf(v0 - mxv) + ((lane < 16) ? expf(v1 - mxv) : 0.0f);
            #pragma unroll
            for (int o = 32; o >= 1; o >>= 1) se += __shfl_xor(se, o);
            float lse = mxv + logf(se);
            float picked = pp[(int)MC];
            m += (double)(lse - picked);

            if (lane == 0) acc += m;   // wave contributes once
        }
    }

    // ---------------- reduction: wave shfl -> 8 doubles -> plain store ----------------
    #pragma unroll
    for (int o = 32; o >= 1; o >>= 1) acc += __shfl_down(acc, o);
    if (lane == 0) dred[wid] = acc;
    __syncthreads();
    if (tid == 0) {
        double v = 0.0;
        #pragma unroll
        for (int w = 0; w < 8; w++) v += dred[w];
        partial[bid] = v;
    }
}

// single-wave reduce: no LDS, no barrier — 8 coalesced loads/thread + shfl tree
__global__ __launch_bounds__(64) void yolo_reduce(const double* __restrict__ partial,
                                                  float* __restrict__ out)
{
    const int tid = threadIdx.x;
    double a = 0.0;
    #pragma unroll
    for (int k = 0; k < 8; k++) a += partial[tid + k*64];   // 512 = 64*8
    #pragma unroll
    for (int o = 32; o >= 1; o >>= 1) a += __shfl_down(a, o);
    if (tid == 0) out[0] = (float)(a / (double)NB);
}

extern "C" void kernel_launch(void* const* d_in, const int* in_sizes, int n_in,
                              void* d_out, int out_size, void* d_ws, size_t ws_size,
                              hipStream_t stream) {
    const float* feat     = (const float*)d_in[0];
    const float* box_pred = (const float*)d_in[1];
    const float* box_conf = (const float*)d_in[2];
    const float* box_prob = (const float*)d_in[3];
    const float* targets  = (const float*)d_in[4];
    const float* anchors  = (const float*)d_in[5];
    double* partial = (double*)d_ws;   // NBLK doubles, fully overwritten each launch
    float* out = (float*)d_out;

    yolo_main<<<NBLK, TPB, 0, stream>>>(
        feat, box_pred, box_conf, box_prob, targets, anchors, partial);
    yolo_reduce<<<1, 64, 0, stream>>>(partial, out);
}